// Round 1
// 1285.389 us; speedup vs baseline: 1.0064x; 1.0064x over previous
//
#include <hip/hip_runtime.h>
#include <stdint.h>
#include <math.h>

#define E_    16
#define NTOK  2048
#define D_    1024
#define H_    4096

typedef unsigned short ushort_t;
typedef __attribute__((ext_vector_type(8))) short short8;
typedef __attribute__((ext_vector_type(4))) float f32x4;

// float -> bf16 round-to-nearest-even (bit trick; inputs are finite)
__device__ __forceinline__ ushort_t f2bf(float f) {
    union { float f; unsigned int u; } v; v.f = f;
    unsigned int u = v.u;
    return (ushort_t)((u + 0x7FFFu + ((u >> 16) & 1u)) >> 16);
}

__device__ __forceinline__ void async_copy16(const void* g, ushort_t* l) {
    __builtin_amdgcn_global_load_lds(
        (const __attribute__((address_space(1))) void*)g,
        (__attribute__((address_space(3))) void*)l,
        16, 0, 0);
}

// ---------------- conversion kernels (unchanged) ----------------

__global__ void cvt_f32_bf16(const float* __restrict__ in, ushort_t* __restrict__ out) {
    int i = blockIdx.x * blockDim.x + threadIdx.x;
    const float4 v = *(const float4*)(in + (size_t)i * 4);
    ushort4 o;
    o.x = f2bf(v.x); o.y = f2bf(v.y); o.z = f2bf(v.z); o.w = f2bf(v.w);
    *(ushort4*)(out + (size_t)i * 4) = o;
}

__global__ void transpose_cvt(const float* __restrict__ in, ushort_t* __restrict__ out,
                              int R, int C) {
    __shared__ float tile[64][65];
    const int e = blockIdx.z;
    const float*  inp  = in  + (size_t)e * R * C;
    ushort_t*     outp = out + (size_t)e * R * C;
    const int c0 = blockIdx.x * 64, r0 = blockIdx.y * 64;
    const int tx = threadIdx.x & 15, ty = threadIdx.x >> 4;
    #pragma unroll
    for (int i = 0; i < 4; ++i) {
        const int r = i * 16 + ty;
        const float4 v = *(const float4*)(inp + (size_t)(r0 + r) * C + c0 + tx * 4);
        tile[r][tx * 4 + 0] = v.x; tile[r][tx * 4 + 1] = v.y;
        tile[r][tx * 4 + 2] = v.z; tile[r][tx * 4 + 3] = v.w;
    }
    __syncthreads();
    #pragma unroll
    for (int i = 0; i < 4; ++i) {
        const int c = i * 16 + ty;
        ushort4 o;
        o.x = f2bf(tile[tx * 4 + 0][c]); o.y = f2bf(tile[tx * 4 + 1][c]);
        o.z = f2bf(tile[tx * 4 + 2][c]); o.w = f2bf(tile[tx * 4 + 3][c]);
        *(ushort4*)(outp + (size_t)(c0 + c) * R + r0 + tx * 4) = o;
    }
}

// ---------------- 256x256 8-phase GEMM (A: MxK rm, Bt: NxK rm, bf16) ----------------
// 512 thr = 8 waves (2M x 4N), per-wave 128x64 out = acc[8][4] of 16x16 frags.
// LDS 128 KiB: per matrix 4 ring slots, each one K-half (256 rows x 32 cols bf16),
// stored as 128 lines x 128B (line = 2 rows), 16B chunk c at phys c^(line&7).
// Slot of K-half u (=2*kt+kk) is u&3 -> all slot indices in the loop are literals.
// Per phase: {ds_reads | stage 1 half-tile (2x global_load_lds w16) | barrier |
//             lgkmcnt(0) | setprio(1) 16xMFMA setprio(0) | barrier}.
// vmcnt(4) only at phases 4 & 8 (counted, never 0 in main loop). Requires K%128==0.

#define BARR()  { asm volatile("" ::: "memory"); __builtin_amdgcn_s_barrier(); \
                  asm volatile("" ::: "memory"); }
#define LGKM0() { asm volatile("s_waitcnt lgkmcnt(0)" ::: "memory"); \
                  __builtin_amdgcn_sched_barrier(0); }
#define VMC(n)  { asm volatile("s_waitcnt vmcnt(" #n ")" ::: "memory"); }

#define SA(s, off) { async_copy16(ag0 + (off), aL0 + (s) * 8192); \
                     async_copy16(ag1 + (off), aL1 + (s) * 8192); }
#define SB(s, off) { async_copy16(bg0 + (off), bL0 + (s) * 8192); \
                     async_copy16(bg1 + (off), bL1 + (s) * 8192); }

#define LDA(s, m) (*(const short8*)&lds[aFB + (s) * 8192 + (m) * 512])
#define LDB(s, n) (*(const short8*)&lds[bFB + (s) * 8192 + (n) * 512])
#define MM(m, n, va, vb) acc[m][n] = __builtin_amdgcn_mfma_f32_16x16x32_bf16(va, vb, acc[m][n], 0, 0, 0)

#define PH_A(s, STG) { \
    a0 = LDA(s, 0); a1 = LDA(s, 1); a2 = LDA(s, 2); a3 = LDA(s, 3); \
    b0 = LDB(s, 0); b1 = LDB(s, 1); b2 = LDB(s, 2); b3 = LDB(s, 3); \
    STG; BARR(); LGKM0(); \
    __builtin_amdgcn_s_setprio(1); \
    MM(0,0,a0,b0); MM(0,1,a0,b1); MM(0,2,a0,b2); MM(0,3,a0,b3); \
    MM(1,0,a1,b0); MM(1,1,a1,b1); MM(1,2,a1,b2); MM(1,3,a1,b3); \
    MM(2,0,a2,b0); MM(2,1,a2,b1); MM(2,2,a2,b2); MM(2,3,a2,b3); \
    MM(3,0,a3,b0); MM(3,1,a3,b1); MM(3,2,a3,b2); MM(3,3,a3,b3); \
    __builtin_amdgcn_s_setprio(0); BARR(); }

#define PH_B(s, STG) { \
    a0 = LDA(s, 4); a1 = LDA(s, 5); a2 = LDA(s, 6); a3 = LDA(s, 7); \
    STG; BARR(); LGKM0(); \
    __builtin_amdgcn_s_setprio(1); \
    MM(4,0,a0,b0); MM(4,1,a0,b1); MM(4,2,a0,b2); MM(4,3,a0,b3); \
    MM(5,0,a1,b0); MM(5,1,a1,b1); MM(5,2,a1,b2); MM(5,3,a1,b3); \
    MM(6,0,a2,b0); MM(6,1,a2,b1); MM(6,2,a2,b2); MM(6,3,a2,b3); \
    MM(7,0,a3,b0); MM(7,1,a3,b1); MM(7,2,a3,b2); MM(7,3,a3,b3); \
    __builtin_amdgcn_s_setprio(0); BARR(); }

template<bool GELU, typename CT>
__global__ __launch_bounds__(512, 2)
void gemm256(const ushort_t* __restrict__ A, const ushort_t* __restrict__ Bt,
             CT* __restrict__ C, int M, int N, int K, int tn, int per_e) {
    __shared__ __align__(16) ushort_t lds[65536];   // 128 KiB

    // bijective XCD swizzle (nwg % 8 == 0 for both launches)
    int wg = blockIdx.x;
    const int cpx = (int)gridDim.x >> 3;
    wg = (wg & 7) * cpx + (wg >> 3);
    const int e  = wg / per_e;
    const int r2 = wg - e * per_e;
    const int bm = r2 / tn;
    const int bn = r2 - bm * tn;

    const int tid  = threadIdx.x;
    const int wave = tid >> 6, lane = tid & 63;
    const int wm = wave >> 2, wn = wave & 3;
    const int lr = lane & 15, cq = lane >> 4;
    const int lh = lr >> 1, lp = lr & 1;
    // fragment read: line = rowbase + m*8 + lh, phys chunk = ((lp*4+cq) ^ lh)
    const int fsw = ((((lp << 2) | cq) ^ lh) << 3);
    const int aFB = (wm * 64 + lh) * 64 + fsw;
    const int bFB = 32768 + (wn * 32 + lh) * 64 + fsw;

    // staging: lane -> (line = slab*8 + l8, phys chunk = lane&7); pre-swizzled source
    const int l8  = lane >> 3;
    const int lc  = (lane & 7) ^ l8;          // logical chunk this lane must fetch
    const int par = lc >> 2, cch = lc & 3;    // row parity, 16B col-chunk

    const size_t K2 = (size_t)K * 2;
    const ushort_t* Ae = A  + (size_t)e * M * K + (size_t)(bm * 256) * K;
    const ushort_t* Be = Bt + (size_t)e * N * K + (size_t)(bn * 256) * K;
    CT* Ce = C + (size_t)e * M * N;

    const char* ag0 = (const char*)Ae + (size_t)(16 * wave + 2 * l8 + par) * K2 + cch * 16;
    const char* ag1 = ag0 + 128 * K2;
    const char* bg0 = (const char*)Be + (size_t)(16 * wave + 2 * l8 + par) * K2 + cch * 16;
    const char* bg1 = bg0 + 128 * K2;
    ushort_t* aL0 = &lds[wave * 512];
    ushort_t* aL1 = &lds[(8 + wave) * 512];
    ushort_t* bL0 = &lds[32768 + wave * 512];
    ushort_t* bL1 = &lds[32768 + (8 + wave) * 512];

    f32x4 acc[8][4];
    #pragma unroll
    for (int i = 0; i < 8; ++i)
        #pragma unroll
        for (int j = 0; j < 4; ++j) acc[i][j] = (f32x4)(0.0f);

    short8 a0, a1, a2, a3, b0, b1, b2, b3;

    // prologue: stage halves u=0..3 (order B0,A0,B1,A1,B2,A2,B3; A3 staged in ph1)
    SB(0, 0); SA(0, 0); SB(1, 64); SA(1, 64); SB(2, 128); SA(2, 128); SB(3, 192);
    VMC(6);               // A0,B0,A1,B1 landed; B2,A2,B3 in flight
    BARR();

    const int T = K >> 7;                 // K/128 iterations, 2 K-tiles each
    for (int t = 0; t < T - 1; ++t) {
        PH_A(0, SA(3, 192));              // stage A(4t+3) -> slot 3
        PH_B(0, SB(0, 256));              // stage B(4t+4) -> slot 0
        PH_A(1, SA(0, 256));              // stage A(4t+4) -> slot 0
        PH_B(1, VMC(4); SB(1, 320));      // drain thru A(4t+3); stage B(4t+5)
        PH_A(2, SA(1, 320));              // stage A(4t+5) -> slot 1
        PH_B(2, SB(2, 384));              // stage B(4t+6) -> slot 2
        PH_A(3, SA(2, 384));              // stage A(4t+6) -> slot 2
        PH_B(3, VMC(4); SB(3, 448));      // drain thru A(4t+5); stage B(4t+7)
        ag0 += 256; ag1 += 256; bg0 += 256; bg1 += 256;
    }
    // final iteration: only A(4T-1) still to stage; drain fully at ph4
    PH_A(0, SA(3, 192));
    PH_B(0, (void)0);
    PH_A(1, (void)0);
    PH_B(1, VMC(0));
    PH_A(2, (void)0);
    PH_B(2, (void)0);
    PH_A(3, (void)0);
    PH_B(3, (void)0);

    // epilogue: C/D 16x16 layout: col = lane&15, row = (lane>>4)*4 + reg
    const int crow = (lane >> 4) * 4;
    const int ccol = lane & 15;
    if constexpr (GELU) {
        // GELU + cvt into LDS (chunk-XOR swizzled: 256x256 bf16 = 128 KiB exactly)
        #pragma unroll
        for (int m = 0; m < 8; ++m) {
            const int rowb = wm * 128 + m * 16 + crow;
            #pragma unroll
            for (int n = 0; n < 4; ++n) {
                const int col = wn * 64 + n * 16 + ccol;
                #pragma unroll
                for (int r = 0; r < 4; ++r) {
                    const int rw = rowb + r;
                    float v = acc[m][n][r];
                    v = 0.5f * v * (1.0f + erff(v * 0.70710678118654752f));
                    lds[rw * 256 + ((((col >> 3) ^ (rw & 31)) << 3) | (col & 7))] = f2bf(v);
                }
            }
        }
        asm volatile("s_waitcnt lgkmcnt(0)" ::: "memory");
        __builtin_amdgcn_s_barrier();
        // coalesced 16B stores: 512 thr x 16 iters cover 256x256
        #pragma unroll
        for (int it = 0; it < 16; ++it) {
            const int row = it * 16 + (tid >> 5);
            const int g8 = tid & 31;
            short8 v = *(const short8*)&lds[row * 256 + ((g8 ^ (row & 31)) << 3)];
            *(short8*)((ushort_t*)Ce + (size_t)(bm * 256 + row) * N + bn * 256 + g8 * 8) = v;
        }
    } else {
        #pragma unroll
        for (int m = 0; m < 8; ++m)
            #pragma unroll
            for (int n = 0; n < 4; ++n)
                #pragma unroll
                for (int r = 0; r < 4; ++r) {
                    const int row = bm * 256 + wm * 128 + m * 16 + crow + r;
                    const int col = bn * 256 + wn * 64 + n * 16 + ccol;
                    Ce[(size_t)row * N + col] = acc[m][n][r];
                }
    }
}

// ---------------- launcher ----------------

extern "C" void kernel_launch(void* const* d_in, const int* in_sizes, int n_in,
                              void* d_out, int out_size, void* d_ws, size_t ws_size,
                              hipStream_t stream) {
    const float* x  = (const float*)d_in[0];   // (E, N, D)
    const float* w1 = (const float*)d_in[1];   // (E, D, H)
    const float* w2 = (const float*)d_in[2];   // (E, H, D)
    float* out = (float*)d_out;                // (E, N, D)

    // workspace layout (bf16 buffers): x_bf | w1t | w2t | hidden
    ushort_t* xb  = (ushort_t*)d_ws;                          // E*N*D
    ushort_t* w1t = xb  + (size_t)E_ * NTOK * D_;             // E*H*D  (w1 -> (H,D))
    ushort_t* w2t = w1t + (size_t)E_ * D_ * H_;               // E*D*H  (w2 -> (D,H))
    ushort_t* hid = w2t + (size_t)E_ * H_ * D_;               // E*N*H

    // 1. convert x to bf16
    {
        const size_t n = (size_t)E_ * NTOK * D_;
        cvt_f32_bf16<<<dim3((unsigned)(n / 4 / 256)), dim3(256), 0, stream>>>(x, xb);
    }
    // 2. transpose-convert weights: w1 (D,H)->(H,D), w2 (H,D)->(D,H)
    transpose_cvt<<<dim3(H_ / 64, D_ / 64, E_), dim3(256), 0, stream>>>(w1, w1t, D_, H_);
    transpose_cvt<<<dim3(D_ / 64, H_ / 64, E_), dim3(256), 0, stream>>>(w2, w2t, H_, D_);

    // 3. GEMM1 + GELU: hid = gelu(x @ w1)   [M=2048, N=4096, K=1024] tiles 8x16 x16e
    gemm256<true, ushort_t><<<dim3(2048), dim3(512), 0, stream>>>(
        xb, w1t, hid, NTOK, H_, D_, 16, 128);

    // 4. GEMM2: out = hid @ w2              [M=2048, N=1024, K=4096] tiles 8x4 x16e
    gemm256<false, float><<<dim3(512), dim3(512), 0, stream>>>(
        hid, w2t, out, NTOK, D_, H_, 4, 32);
}